// Round 3
// baseline (17997.581 us; speedup 1.0000x reference)
//
#include <hip/hip_runtime.h>

// LSTM: B=64, S=512, D=H=O=1024.
// R3 change: the 512 per-step kernels are replaced by ONE persistent
// cooperative kernel (256 blocks, 1/CU). Wh slice resident in LDS, c-state
// resident in registers, h read direct-from-global in MFMA A-layout, one
// device-scope sense-reversing grid barrier per step.
//
// Pipeline:
//  1) convert x -> bf16, transposed to [s][b][d]
//  2) pack Wx,Wh -> bf16 rows n' = k*4 + gate (gate-interleaved)
//  3) xg = x @ Wx^T  (bf16 MFMA GEMM, 32768x4096x1024), stored bf16
//  4) persistent recurrence kernel: 512 steps, grid barrier per step
//  5) y = h_all @ Wp^T + bp  (32768x1024x1024), scattered to out[b][s][o]
//  6) tail: final (c,h) f32 -> out

typedef unsigned short u16;
typedef u16   u16x4  __attribute__((ext_vector_type(4)));
typedef u16   u16x8  __attribute__((ext_vector_type(8)));
typedef __bf16 bf16x8 __attribute__((ext_vector_type(8)));
typedef float f32x4  __attribute__((ext_vector_type(4)));

__device__ __forceinline__ u16 f2bf(float x) {
    unsigned u = __float_as_uint(x);
    u = (u + 0x7FFFu + ((u >> 16) & 1u)) >> 16;   // RNE
    return (u16)u;
}
__device__ __forceinline__ float bf2f(u16 h) {
    return __uint_as_float(((unsigned)h) << 16);
}
__device__ __forceinline__ float fsig(float x) { return 1.f / (1.f + __expf(-x)); }
__device__ __forceinline__ float ftanh(float x) { return 1.f - 2.f / (__expf(2.f * x) + 1.f); }

// ---- conversion / packing kernels -----------------------------------------

// x[b][s][d] f32 -> xb[(s*64+b)][d] bf16.  grid = B*S blocks, 256 thr.
__global__ void k_convert_x(const float* __restrict__ x, u16* __restrict__ xb) {
    int bi = blockIdx.x;            // = b*512 + s  (x row order)
    int b = bi >> 9, s = bi & 511;
    const float4* src = (const float4*)(x + (size_t)bi * 1024);
    u16* dst = xb + ((size_t)(s * 64 + b)) * 1024;
    int t = threadIdx.x;
    float4 v = src[t];
    u16x4 o; o.x = f2bf(v.x); o.y = f2bf(v.y); o.z = f2bf(v.z); o.w = f2bf(v.w);
    *(u16x4*)(dst + t * 4) = o;
}

// W[4][1024][1024] f32 -> wp[n'=k*4+g][1024] bf16.  grid = 4096 blocks.
__global__ void k_pack_gates(const float* __restrict__ w, u16* __restrict__ wp) {
    int np = blockIdx.x;
    int g = np & 3, k = np >> 2;
    const float4* src = (const float4*)(w + ((size_t)(g * 1024 + k)) * 1024);
    u16* dst = wp + (size_t)np * 1024;
    int t = threadIdx.x;
    float4 v = src[t];
    u16x4 o; o.x = f2bf(v.x); o.y = f2bf(v.y); o.z = f2bf(v.z); o.w = f2bf(v.w);
    *(u16x4*)(dst + t * 4) = o;
}

// plain f32 -> bf16 copy (Wp). n must be multiple of 1024.
__global__ void k_f2bf(const float* __restrict__ src, u16* __restrict__ dst, int n) {
    int i = (blockIdx.x * 256 + threadIdx.x) * 4;
    if (i < n) {
        float4 v = *(const float4*)(src + i);
        u16x4 o; o.x = f2bf(v.x); o.y = f2bf(v.y); o.z = f2bf(v.z); o.w = f2bf(v.w);
        *(u16x4*)(dst + i) = o;
    }
}

// bias[n'] = bx[g][k] + bh[g][k], n' = k*4+g. 4096 elems.
__global__ void k_bias(const float* __restrict__ bx, const float* __restrict__ bh,
                       float* __restrict__ bias) {
    int np = blockIdx.x * 256 + threadIdx.x;
    int g = np & 3, k = np >> 2;
    bias[np] = bx[g * 1024 + k] + bh[g * 1024 + k];
}

// zero h[slot 0], c state, and barrier state. 65536 threads.
__global__ void k_init(u16* __restrict__ hall0, float* __restrict__ cstate,
                       unsigned* __restrict__ bar) {
    int i = blockIdx.x * 256 + threadIdx.x;
    hall0[i] = 0;
    cstate[i] = 0.f;
    if (i < 4) bar[i] = 0u;   // cnt[0], cnt[1], gen, pad
}

// ---- generic 64x64-tile bf16 GEMM (C = A @ Bt^T) --------------------------
// A: [M][K] bf16 row-major. Bt: [N][K] bf16 row-major.
// mode 0: Cb[m*N + n] = bf16(acc)                      (xg precompute)
// mode 1: Cf[(b*S_ + s)*O_ + n] = acc + bp[n], m=s*64+b (output projection)
__global__ __launch_bounds__(256) void k_gemm64(
    const u16* __restrict__ A, const u16* __restrict__ Bt,
    int K, int N, int mode,
    u16* __restrict__ Cb,
    float* __restrict__ Cf, const float* __restrict__ bp, int S_, int O_) {
    __shared__ u16 As[64 * 72];   // +8 pad
    __shared__ u16 Bs[64 * 72];
    int mb = blockIdx.x, nb = blockIdx.y;
    int tid = threadIdx.x, w = tid >> 6, lane = tid & 63;
    f32x4 acc[4] = {};
    int kchunks = K >> 6;
    for (int kc = 0; kc < kchunks; ++kc) {
        int k0 = kc * 64;
#pragma unroll
        for (int r = 0; r < 2; ++r) {
            int c = tid + 256 * r;            // 0..511: 16B chunks
            int row = c >> 3, kk = (c & 7) * 8;
            *(u16x8*)(&As[row * 72 + kk]) =
                *(const u16x8*)(A + (size_t)(mb * 64 + row) * K + k0 + kk);
            *(u16x8*)(&Bs[row * 72 + kk]) =
                *(const u16x8*)(Bt + (size_t)(nb * 64 + row) * K + k0 + kk);
        }
        __syncthreads();
#pragma unroll
        for (int kk = 0; kk < 64; kk += 32) {
            bf16x8 a = *(const bf16x8*)(&As[(w * 16 + (lane & 15)) * 72 + kk + (lane >> 4) * 8]);
#pragma unroll
            for (int nt = 0; nt < 4; ++nt) {
                bf16x8 b = *(const bf16x8*)(&Bs[(nt * 16 + (lane & 15)) * 72 + kk + (lane >> 4) * 8]);
                acc[nt] = __builtin_amdgcn_mfma_f32_16x16x32_bf16(a, b, acc[nt], 0, 0, 0);
            }
        }
        __syncthreads();
    }
    int q = lane >> 4, cl = lane & 15;
    if (mode == 0) {
#pragma unroll
        for (int nt = 0; nt < 4; ++nt)
#pragma unroll
            for (int j = 0; j < 4; ++j) {
                int m = mb * 64 + w * 16 + q * 4 + j;
                int n = nb * 64 + nt * 16 + cl;
                Cb[(size_t)m * N + n] = f2bf(acc[nt][j]);
            }
    } else {
#pragma unroll
        for (int nt = 0; nt < 4; ++nt)
#pragma unroll
            for (int j = 0; j < 4; ++j) {
                int m = mb * 64 + w * 16 + q * 4 + j;
                int n = nb * 64 + nt * 16 + cl;
                int b = m & 63, s = m >> 6;
                Cf[((size_t)b * S_ + s) * O_ + n] = acc[nt][j] + bp[n];
            }
    }
}

// ---- persistent recurrence kernel -----------------------------------------
// 256 blocks (cooperative, 1/CU). Block nb owns cols n = nb*16..nb*16+15
// (= k-values nb*4..nb*4+3, all 4 gates). Wh slice persistent in LDS.
// c-state in registers (thread tid owns (row=tid>>2, kv=tid&3)).
// One grid barrier per step; h ring in hall[] (bf16) is the only cross-block
// data, released/acquired with agent-scope fences (cross-XCD safe).
__global__ __launch_bounds__(256) void k_recur(
    const u16* __restrict__ whp,     // [4096][1024] bf16, gate-interleaved
    const u16* __restrict__ xg,      // [512][64][4096] bf16
    const float* __restrict__ bias,  // [4096]
    u16* __restrict__ hall,          // [513][64][1024] bf16 (slot 0 zeroed)
    float* __restrict__ cst,         // [64][1024] f32 out (final c)
    float* __restrict__ hf32,        // [64][1024] f32 out (final h)
    unsigned* __restrict__ bar) {    // {cnt0, cnt1, gen, pad} zeroed
    __shared__ u16 Bs[16 * 1032];    // Wh slice, 33 KB (+8 elem pad/row)
    __shared__ float glds[64 * 20];  // g tile for epilogue, 5 KB
    int nb = blockIdx.x;             // 0..255
    int tid = threadIdx.x, w = tid >> 6, lane = tid & 63;
    int q = lane >> 4, cl = lane & 15;

    // stage Wh slice once: 16 rows x 1024 = 2048 x 16B chunks, 8/thread
#pragma unroll
    for (int r = 0; r < 8; ++r) {
        int c = tid + 256 * r;            // 0..2047
        int row = c >> 7, kk = (c & 127) * 8;
        *(u16x8*)(&Bs[row * 1032 + kk]) =
            *(const u16x8*)(whp + (size_t)(nb * 16 + row) * 1024 + kk);
    }
    float bcol = bias[nb * 16 + cl];      // per-lane column bias
    // gate-math role
    int grow = tid >> 2, gkv = tid & 3;
    int gk = nb * 4 + gkv;
    float c_reg = 0.f, h_last = 0.f;
    __syncthreads();

    for (int t = 0; t < 512; ++t) {
        // prefetch this step's xg values (independent of h, HBM-cold)
        const u16* xgt = xg + (size_t)t * 64 * 4096;
        int row0 = w * 16 + q * 4;
        int ncol = nb * 16 + cl;
        u16 xv0 = xgt[(size_t)(row0 + 0) * 4096 + ncol];
        u16 xv1 = xgt[(size_t)(row0 + 1) * 4096 + ncol];
        u16 xv2 = xgt[(size_t)(row0 + 2) * 4096 + ncol];
        u16 xv3 = xgt[(size_t)(row0 + 3) * 4096 + ncol];
        // K-loop: A direct from global (MFMA A-layout), B from LDS
        const u16* hrow = hall + (size_t)t * 65536 + (size_t)(w * 16 + cl) * 1024 + q * 8;
        f32x4 acc = {};
#pragma unroll
        for (int kk = 0; kk < 1024; kk += 32) {
            bf16x8 a = *(const bf16x8*)(hrow + kk);
            bf16x8 b = *(const bf16x8*)(&Bs[cl * 1032 + kk + q * 8]);
            acc = __builtin_amdgcn_mfma_f32_16x16x32_bf16(a, b, acc, 0, 0, 0);
        }
        // g = acc + xg + bias -> LDS
        glds[(row0 + 0) * 20 + cl] = acc[0] + bf2f(xv0) + bcol;
        glds[(row0 + 1) * 20 + cl] = acc[1] + bf2f(xv1) + bcol;
        glds[(row0 + 2) * 20 + cl] = acc[2] + bf2f(xv2) + bcol;
        glds[(row0 + 3) * 20 + cl] = acc[3] + bf2f(xv3) + bcol;
        __syncthreads();
        // gate math: thread owns (grow, gkv)
        float4 gv = *(const float4*)(&glds[grow * 20 + gkv * 4]);
        float ig = fsig(gv.x), fg = fsig(gv.y), og = fsig(gv.z), cc = ftanh(gv.w);
        c_reg = fg * c_reg + ig * cc;
        h_last = og * ftanh(c_reg);
        hall[(size_t)(t + 1) * 65536 + grow * 1024 + gk] = f2bf(h_last);
        __syncthreads();   // glds safe to overwrite next step
        // grid barrier: release h writes, wait all, acquire
        if (tid == 0) {
            __builtin_amdgcn_fence(__ATOMIC_RELEASE, "agent");
            unsigned p = (unsigned)t & 1u;
            unsigned my = __hip_atomic_fetch_add(&bar[p], 1u, __ATOMIC_ACQ_REL,
                                                 __HIP_MEMORY_SCOPE_AGENT);
            if (my == 255u) {
                __hip_atomic_store(&bar[p], 0u, __ATOMIC_RELAXED,
                                   __HIP_MEMORY_SCOPE_AGENT);
                __hip_atomic_fetch_add(&bar[2], 1u, __ATOMIC_RELEASE,
                                       __HIP_MEMORY_SCOPE_AGENT);
            } else {
                while (__hip_atomic_load(&bar[2], __ATOMIC_ACQUIRE,
                                         __HIP_MEMORY_SCOPE_AGENT) < (unsigned)(t + 1)) {}
            }
            __builtin_amdgcn_fence(__ATOMIC_ACQUIRE, "agent");
        }
        __syncthreads();
    }
    // final state out
    cst[grow * 1024 + gk] = c_reg;
    hf32[grow * 1024 + gk] = h_last;
}

// final (c,h) -> d_out tail. 131072 elems.
__global__ void k_tail(const float* __restrict__ cstate, const float* __restrict__ hf32,
                       float* __restrict__ out) {
    int i = blockIdx.x * 256 + threadIdx.x;
    if (i < 65536) out[33554432 + i] = cstate[i];
    else           out[33554432 + i] = hf32[i - 65536];
}

extern "C" void kernel_launch(void* const* d_in, const int* in_sizes, int n_in,
                              void* d_out, int out_size, void* d_ws, size_t ws_size,
                              hipStream_t stream) {
    const float* x  = (const float*)d_in[0];
    const float* Wx = (const float*)d_in[1];
    const float* bx = (const float*)d_in[2];
    const float* Wh = (const float*)d_in[3];
    const float* bh = (const float*)d_in[4];
    const float* Wp = (const float*)d_in[5];
    const float* bp = (const float*)d_in[6];
    float* out = (float*)d_out;
    char* ws = (char*)d_ws;

    // workspace layout (bytes), total ~422 MB
    u16*      xb   = (u16*)     (ws);                   // 64 MB  [32768][1024] bf16
    u16*      wxp  = (u16*)     (ws + 67108864);        // 8 MB   [4096][1024]
    u16*      whp  = (u16*)     (ws + 75497472);        // 8 MB   [4096][1024]
    u16*      wpb  = (u16*)     (ws + 83886080);        // 2 MB   [1024][1024]
    float*    bias = (float*)   (ws + 85983232);        // 16 KB  [4096]
    float*    cst  = (float*)   (ws + 85999616);        // 256 KB [64][1024]
    float*    hf32 = (float*)   (ws + 86261760);        // 256 KB [64][1024]
    unsigned* bar  = (unsigned*)(ws + 86523648);        // 16 B   barrier state
    u16*      xg   = (u16*)     (ws + 86523904);        // 256 MB [32768][4096]
    u16*      hall = (u16*)     (ws + 354959360);       // 64.1 MB [513][64][1024]

    k_convert_x<<<32768, 256, 0, stream>>>(x, xb);
    k_pack_gates<<<4096, 256, 0, stream>>>(Wx, wxp);
    k_pack_gates<<<4096, 256, 0, stream>>>(Wh, whp);
    k_f2bf<<<1024, 256, 0, stream>>>(Wp, wpb, 1048576);
    k_bias<<<16, 256, 0, stream>>>(bx, bh, bias);
    k_init<<<256, 256, 0, stream>>>(hall, cst, bar);

    // xg = x @ Wx^T : M=32768, N=4096, K=1024
    k_gemm64<<<dim3(512, 64), 256, 0, stream>>>(xb, wxp, 1024, 4096, 0,
                                                xg, nullptr, nullptr, 0, 0);
    // persistent recurrence: 512 steps in one cooperative kernel
    {
        void* args[] = {(void*)&whp, (void*)&xg, (void*)&bias, (void*)&hall,
                        (void*)&cst, (void*)&hf32, (void*)&bar};
        hipLaunchCooperativeKernel((const void*)k_recur, dim3(256), dim3(256),
                                   args, 0, stream);
    }
    // y = h_all @ Wp^T : M=32768, N=1024, K=1024; scatter to out[b][s][o]
    k_gemm64<<<dim3(512, 16), 256, 0, stream>>>(hall + 65536, wpb, 1024, 1024, 1,
                                                nullptr, out, bp, 512, 1024);
    k_tail<<<512, 256, 0, stream>>>(cst, hf32, out);
}